// Round 1
// baseline (1134.211 us; speedup 1.0000x reference)
//
#include <hip/hip_runtime.h>

// Problem constants (from setup_inputs): z (8,256,32,32), weight (16384,256)
#define NB   8
#define DIM  256
#define HH   32
#define WW   32
#define HW   1024          // 32*32
#define NZ   8192          // NB*HW flattened z rows
#define KC   16384         // codebook entries
#define DECAYF 0.99f
#define ONEMDECAY 0.01f
#define EPSF 1e-5f
#define BETAF 0.25f

// Output offsets (floats) in d_out, in reference return order
#define O_ZQ   0u
#define O_LOSS 2097152u
#define O_PERP 2097153u
#define O_IDX  2097154u
#define O_NW   2105346u
#define O_NCS  6299650u
#define O_NEA  6316034u

// ws layout (floats)
#define W_ZT     0u         // 8192*256
#define W_WSQ    2097152u   // 16384
#define W_CNT    2113536u   // 16384
#define W_SCAL   2129920u   // 4: [0]=loss_sum [1]=n_sum [2]=plogp
#define W_PACKED 2129924u   // 8192 u64 (even float offset -> 8B aligned)
#define WS_FLOATS (2129924u + 16384u)

// ---------------- K0: transpose z (b,c,h,w) -> zt[n][d], n = b*1024+hw ----------
__global__ void k_transpose_in(const float* __restrict__ z, float* __restrict__ zt) {
  __shared__ float tile[64][65];
  int hwb = blockIdx.x * 64, db = blockIdx.y * 64, b = blockIdx.z;
  int lane = threadIdx.x & 63, sub = threadIdx.x >> 6;
#pragma unroll
  for (int i = 0; i < 16; ++i) {
    int dof = sub * 16 + i;
    tile[dof][lane] = z[((size_t)(b * DIM + db + dof)) * HW + hwb + lane];
  }
  __syncthreads();
#pragma unroll
  for (int i = 0; i < 16; ++i) {
    int hwof = sub * 16 + i;
    zt[((size_t)(b * HW + hwb + hwof)) * DIM + db + lane] = tile[lane][hwof];
  }
}

// ---------------- K5: transpose zt[n][d] (holds z_q_st) -> out0 (b,c,h,w) -------
__global__ void k_transpose_out(const float* __restrict__ zt, float* __restrict__ out0) {
  __shared__ float tile[64][65];
  int hwb = blockIdx.x * 64, db = blockIdx.y * 64, b = blockIdx.z;
  int lane = threadIdx.x & 63, sub = threadIdx.x >> 6;
#pragma unroll
  for (int i = 0; i < 16; ++i) {
    int hwof = sub * 16 + i;
    tile[hwof][lane] = zt[((size_t)(b * HW + hwb + hwof)) * DIM + db + lane];
  }
  __syncthreads();
#pragma unroll
  for (int i = 0; i < 16; ++i) {
    int dof = sub * 16 + i;
    out0[((size_t)(b * DIM + db + dof)) * HW + hwb + lane] = tile[lane][dof];
  }
}

// ---------------- K1: wsq[k] = sum_d w[k][d]^2 ----------------------------------
__global__ void k_wsq(const float* __restrict__ w, float* __restrict__ wsq) {
  int wave = threadIdx.x >> 6, lane = threadIdx.x & 63;
  int k = blockIdx.x * 4 + wave;
  float4 v = *(const float4*)&w[(size_t)k * DIM + lane * 4];
  float s = v.x * v.x + v.y * v.y + v.z * v.z + v.w * v.w;
#pragma unroll
  for (int off = 32; off; off >>= 1) s += __shfl_down(s, off);
  if (lane == 0) wsq[k] = s;
}

// ---------------- K1b: init new_embed_avg output with 0.99*embed_avg ------------
__global__ void k_init_embed(const float* __restrict__ ea, float* __restrict__ out6) {
  size_t i = (size_t)blockIdx.x * 256 + threadIdx.x;
  out6[i] = DECAYF * ea[i];
}

// ---------------- K2: fused distance GEMM + argmin ------------------------------
// score[n][k] = wsq[k] - 2*dot(zt[n], w[k]); argmin over k via packed u64 atomicMin.
#define TM 128
#define TN 128
#define DK 32
#define PADL 33
__global__ __launch_bounds__(256) void k_argmin(const float* __restrict__ zt,
                                                const float* __restrict__ w,
                                                const float* __restrict__ wsq,
                                                unsigned long long* __restrict__ packed) {
  __shared__ float As[TM * PADL];
  __shared__ float Ws[TN * PADL];
  __shared__ unsigned long long best[TM];
  const int tid = threadIdx.x;
  const int k0 = blockIdx.x * TN, m0 = blockIdx.y * TM;
  if (tid < TM) best[tid] = 0xFFFFFFFFFFFFFFFFull;
  const int tx = tid & 15, ty = tid >> 4;
  const int mrow = tid & 127;
  const int q = (tid >> 7) * 16;   // each row staged by 2 threads, 16 floats each

  float acc[8][8];
#pragma unroll
  for (int i = 0; i < 8; ++i)
#pragma unroll
    for (int j = 0; j < 8; ++j) acc[i][j] = 0.0f;

  for (int dbase = 0; dbase < DIM; dbase += DK) {
    __syncthreads();
    // stage A (zt rows m0..m0+127, d window) and W (w rows k0..k0+127)
    const float* za = &zt[(size_t)(m0 + mrow) * DIM + dbase + q];
    const float* wa = &w[(size_t)(k0 + mrow) * DIM + dbase + q];
    float4 a0 = *(const float4*)(za + 0), a1 = *(const float4*)(za + 4);
    float4 a2 = *(const float4*)(za + 8), a3 = *(const float4*)(za + 12);
    float4 b0 = *(const float4*)(wa + 0), b1 = *(const float4*)(wa + 4);
    float4 b2 = *(const float4*)(wa + 8), b3 = *(const float4*)(wa + 12);
    float* Ap = &As[mrow * PADL + q];
    float* Wp = &Ws[mrow * PADL + q];
    Ap[0] = a0.x; Ap[1] = a0.y; Ap[2] = a0.z; Ap[3] = a0.w;
    Ap[4] = a1.x; Ap[5] = a1.y; Ap[6] = a1.z; Ap[7] = a1.w;
    Ap[8] = a2.x; Ap[9] = a2.y; Ap[10] = a2.z; Ap[11] = a2.w;
    Ap[12] = a3.x; Ap[13] = a3.y; Ap[14] = a3.z; Ap[15] = a3.w;
    Wp[0] = b0.x; Wp[1] = b0.y; Wp[2] = b0.z; Wp[3] = b0.w;
    Wp[4] = b1.x; Wp[5] = b1.y; Wp[6] = b1.z; Wp[7] = b1.w;
    Wp[8] = b2.x; Wp[9] = b2.y; Wp[10] = b2.z; Wp[11] = b2.w;
    Wp[12] = b3.x; Wp[13] = b3.y; Wp[14] = b3.z; Wp[15] = b3.w;
    __syncthreads();
#pragma unroll
    for (int d = 0; d < DK; ++d) {
      float a[8], b[8];
#pragma unroll
      for (int i = 0; i < 4; ++i) {
        a[i]     = As[(ty * 4 + i) * PADL + d];
        a[4 + i] = As[(64 + ty * 4 + i) * PADL + d];
        b[i]     = Ws[(tx * 4 + i) * PADL + d];
        b[4 + i] = Ws[(64 + tx * 4 + i) * PADL + d];
      }
#pragma unroll
      for (int i = 0; i < 8; ++i)
#pragma unroll
        for (int j = 0; j < 8; ++j) acc[i][j] = fmaf(a[i], b[j], acc[i][j]);
    }
  }

  // epilogue: per-row argmin over this block's 128 codes
  float sc[8];
  int cols[8];
#pragma unroll
  for (int j = 0; j < 8; ++j) {
    int c = (j < 4) ? tx * 4 + j : 64 + tx * 4 + (j - 4);
    cols[j] = k0 + c;
    sc[j] = wsq[cols[j]];
  }
#pragma unroll
  for (int i = 0; i < 8; ++i) {
    int r = (i < 4) ? ty * 4 + i : 64 + ty * 4 + (i - 4);
    unsigned long long bv = 0xFFFFFFFFFFFFFFFFull;
#pragma unroll
    for (int j = 0; j < 8; ++j) {
      float score = fmaf(-2.0f, acc[i][j], sc[j]);
      unsigned u = __float_as_uint(score);
      u ^= (unsigned)(((int)u >> 31) | 0x80000000);  // monotonic float->uint
      unsigned long long p = ((unsigned long long)u << 32) | (unsigned)cols[j];
      bv = p < bv ? p : bv;
    }
    atomicMin(&best[r], bv);
  }
  __syncthreads();
  if (tid < TM) atomicMin(&packed[m0 + tid], best[tid]);
}

// ---------------- K3a: extract indices, histogram counts ------------------------
__global__ void k_idx(const unsigned long long* __restrict__ packed,
                      float* __restrict__ out3, float* __restrict__ counts) {
  int n = blockIdx.x * 256 + threadIdx.x;
  int k = (int)(packed[n] & 0xFFFFFFFFull);
  out3[n] = (float)k;
  atomicAdd(&counts[k], 1.0f);
}

// ---------------- K3b: z_q gather, loss, embed_sum scatter, z_q_st in-place -----
__global__ __launch_bounds__(256) void k_scatter(float* __restrict__ zt,
                                                 const float* __restrict__ w,
                                                 const unsigned long long* __restrict__ packed,
                                                 float* __restrict__ emb_out,
                                                 float* __restrict__ loss_sum) {
  int n = blockIdx.x, d = threadIdx.x;
  int k = (int)(packed[n] & 0xFFFFFFFFull);
  float zv = zt[(size_t)n * DIM + d];
  float wv = w[(size_t)k * DIM + d];
  float diff = wv - zv;                       // z_q - z_perm
  zt[(size_t)n * DIM + d] = zv + diff;        // straight-through (matches ref fp order)
  atomicAdd(&emb_out[(size_t)k * DIM + d], ONEMDECAY * zv);
  float v = diff * diff;
#pragma unroll
  for (int off = 32; off; off >>= 1) v += __shfl_down(v, off);
  __shared__ float red[4];
  if ((threadIdx.x & 63) == 0) red[threadIdx.x >> 6] = v;
  __syncthreads();
  if (threadIdx.x == 0) atomicAdd(loss_sum, red[0] + red[1] + red[2] + red[3]);
}

// ---------------- K4a: new_cluster_size, n_sum, perplexity partial --------------
__global__ void k_cs(const float* __restrict__ cs, const float* __restrict__ counts,
                     float* __restrict__ out5, float* __restrict__ scal) {
  int k = blockIdx.x * 256 + threadIdx.x;
  float c = counts[k];
  float ncs = cs[k] * DECAYF + ONEMDECAY * c;
  out5[k] = ncs;
  float p = c * (1.0f / (float)NZ);
  float t = p * logf(p + 1e-10f);
#pragma unroll
  for (int off = 32; off; off >>= 1) {
    ncs += __shfl_down(ncs, off);
    t += __shfl_down(t, off);
  }
  __shared__ float r1[4], r2[4];
  if ((threadIdx.x & 63) == 0) { r1[threadIdx.x >> 6] = ncs; r2[threadIdx.x >> 6] = t; }
  __syncthreads();
  if (threadIdx.x == 0) {
    atomicAdd(&scal[1], r1[0] + r1[1] + r1[2] + r1[3]);
    atomicAdd(&scal[2], r2[0] + r2[1] + r2[2] + r2[3]);
  }
}

// ---------------- K4b: new_weight + scalars -------------------------------------
__global__ void k_final(const float* __restrict__ emb_out, const float* __restrict__ out5,
                        const float* __restrict__ scal, float* __restrict__ out4,
                        float* __restrict__ out1, float* __restrict__ out2) {
  size_t i = (size_t)blockIdx.x * 256 + threadIdx.x;
  float n = scal[1];
  int k = (int)(i >> 8);
  float ncs = out5[k];
  float smoothed = (ncs + EPSF) / (n + (float)KC * EPSF) * n;
  out4[i] = emb_out[i] / smoothed;
  if (i == 0) {
    out1[0] = BETAF * scal[0] / (float)(NZ * DIM);
    out2[0] = expf(-scal[2]);
  }
}

extern "C" void kernel_launch(void* const* d_in, const int* in_sizes, int n_in,
                              void* d_out, int out_size, void* d_ws, size_t ws_size,
                              hipStream_t stream) {
  const float* z  = (const float*)d_in[0];
  const float* w  = (const float*)d_in[1];
  const float* cs = (const float*)d_in[2];
  const float* ea = (const float*)d_in[3];
  float* out = (float*)d_out;
  float* ws  = (float*)d_ws;

  if (ws_size < (size_t)WS_FLOATS * sizeof(float)) return;  // fail loudly (poison stays)

  float* zt     = ws + W_ZT;
  float* wsq    = ws + W_WSQ;
  float* counts = ws + W_CNT;
  float* scal   = ws + W_SCAL;
  unsigned long long* packed = (unsigned long long*)(ws + W_PACKED);

  float* out0 = out + O_ZQ;
  float* out1 = out + O_LOSS;
  float* out2 = out + O_PERP;
  float* out3 = out + O_IDX;
  float* out4 = out + O_NW;
  float* out5 = out + O_NCS;
  float* out6 = out + O_NEA;

  hipMemsetAsync(counts, 0, (16384 + 4) * sizeof(float), stream);          // counts + scalars
  hipMemsetAsync(packed, 0xFF, (size_t)NZ * sizeof(unsigned long long), stream);

  k_transpose_in<<<dim3(16, 4, NB), 256, 0, stream>>>(z, zt);
  k_wsq<<<KC / 4, 256, 0, stream>>>(w, wsq);
  k_init_embed<<<(KC * DIM) / 256, 256, 0, stream>>>(ea, out6);
  k_argmin<<<dim3(KC / TN, NZ / TM), 256, 0, stream>>>(zt, w, wsq, packed);
  k_idx<<<NZ / 256, 256, 0, stream>>>(packed, out3, counts);
  k_scatter<<<NZ, 256, 0, stream>>>(zt, w, packed, out6, scal);
  k_cs<<<KC / 256, 256, 0, stream>>>(cs, counts, out5, scal);
  k_final<<<(KC * DIM) / 256, 256, 0, stream>>>(out6, out5, scal, out4, out1, out2);
  k_transpose_out<<<dim3(16, 4, NB), 256, 0, stream>>>(zt, out0);
}

// Round 3
// 495.343 us; speedup vs baseline: 2.2897x; 2.2897x over previous
//
#include <hip/hip_runtime.h>

// Problem constants (from setup_inputs): z (8,256,32,32), weight (16384,256)
#define NB   8
#define DIM  256
#define HW   1024          // 32*32
#define NZ   8192          // NB*HW flattened z rows
#define KC   16384         // codebook entries
#define DECAYF 0.99f
#define ONEMDECAY 0.01f
#define EPSF 1e-5f
#define BETAF 0.25f
#define KCAT 768           // split-GEMM K: [ah|al|ah] . [bh|bh|bl]

typedef _Float16 half8 __attribute__((ext_vector_type(8)));
typedef _Float16 half4 __attribute__((ext_vector_type(4)));
typedef float floatx4 __attribute__((ext_vector_type(4)));

// Output offsets (floats) in d_out, in reference return order
#define O_ZQ   0u
#define O_LOSS 2097152u
#define O_PERP 2097153u
#define O_IDX  2097154u
#define O_NW   2105346u
#define O_NCS  6299650u
#define O_NEA  6316034u

// ws layout (floats)
#define W_ZT     0u          // 8192*256 fp32
#define W_WSQ    2097152u    // 16384
#define W_CNT    2113536u    // 16384
#define W_SCAL   2129920u    // 4: [0]=loss_sum [1]=n_sum [2]=plogp
#define W_PACKED 2129924u    // 8192 u64 (byte off % 8 == 0)
#define W_ACAT   2146308u    // 8192*768 f16 (byte off % 16 == 0)
#define W_BCAT   5292036u    // 16384*768 f16 (byte off % 16 == 0)
#define WS_FLOATS_OLD 2146308u
#define WS_FLOATS_NEW 11583492u

// ---------------- K0: transpose z (b,c,h,w) -> zt[n][d] (+ optional f16 Acat) ---
// Acat segments: [ah | al | ah] so that with Bcat = [bh | bh | bl]:
//   dot = ah.bh + al.bh + ah.bl  (compensated product; only al.bl dropped)
template <bool SPLIT>
__global__ void k_transpose_in(const float* __restrict__ z, float* __restrict__ zt,
                               _Float16* __restrict__ Acat) {
  __shared__ float tile[64][65];
  int hwb = blockIdx.x * 64, db = blockIdx.y * 64, b = blockIdx.z;
  int lane = threadIdx.x & 63, sub = threadIdx.x >> 6;
#pragma unroll
  for (int i = 0; i < 16; ++i) {
    int dof = sub * 16 + i;
    tile[dof][lane] = z[((size_t)(b * DIM + db + dof)) * HW + hwb + lane];
  }
  __syncthreads();
#pragma unroll
  for (int i = 0; i < 16; ++i) {
    int hwof = sub * 16 + i;
    int n = b * HW + hwb + hwof;
    float val = tile[lane][hwof];
    zt[(size_t)n * DIM + db + lane] = val;
    if (SPLIT) {
      _Float16 h = (_Float16)val;
      _Float16 lo = (_Float16)(val - (float)h);
      size_t abase = (size_t)n * KCAT + db + lane;
      Acat[abase] = h;          // seg0 = ah
      Acat[abase + 256] = lo;   // seg1 = al   (pairs with bh)
      Acat[abase + 512] = h;    // seg2 = ah   (pairs with bl)
    }
  }
}

// ---------------- K5: transpose zt[n][d] (holds z_q_st) -> out0 (b,c,h,w) -------
__global__ void k_transpose_out(const float* __restrict__ zt, float* __restrict__ out0) {
  __shared__ float tile[64][65];
  int hwb = blockIdx.x * 64, db = blockIdx.y * 64, b = blockIdx.z;
  int lane = threadIdx.x & 63, sub = threadIdx.x >> 6;
#pragma unroll
  for (int i = 0; i < 16; ++i) {
    int hwof = sub * 16 + i;
    tile[hwof][lane] = zt[((size_t)(b * HW + hwb + hwof)) * DIM + db + lane];
  }
  __syncthreads();
#pragma unroll
  for (int i = 0; i < 16; ++i) {
    int dof = sub * 16 + i;
    out0[((size_t)(b * DIM + db + dof)) * HW + hwb + lane] = tile[lane][dof];
  }
}

// ---------------- K1: wsq[k] = sum_d w[k][d]^2 (fp32) + optional f16 Bcat -------
template <bool SPLIT>
__global__ void k_prep_w(const float* __restrict__ w, float* __restrict__ wsq,
                         _Float16* __restrict__ Bcat) {
  int wave = threadIdx.x >> 6, lane = threadIdx.x & 63;
  int k = blockIdx.x * 4 + wave;
  float4 v = *(const float4*)&w[(size_t)k * DIM + lane * 4];
  float s = v.x * v.x + v.y * v.y + v.z * v.z + v.w * v.w;
#pragma unroll
  for (int off = 32; off; off >>= 1) s += __shfl_down(s, off);
  if (lane == 0) wsq[k] = s;
  if (SPLIT) {
    half4 h = { (_Float16)v.x, (_Float16)v.y, (_Float16)v.z, (_Float16)v.w };
    half4 lo = { (_Float16)(v.x - (float)h.x), (_Float16)(v.y - (float)h.y),
                 (_Float16)(v.z - (float)h.z), (_Float16)(v.w - (float)h.w) };
    size_t bbase = (size_t)k * KCAT + lane * 4;
    *(half4*)&Bcat[bbase] = h;          // seg0 = bh
    *(half4*)&Bcat[bbase + 256] = h;    // seg1 = bh
    *(half4*)&Bcat[bbase + 512] = lo;   // seg2 = bl
  }
}

// ---------------- K1b: init new_embed_avg output with 0.99*embed_avg ------------
__global__ void k_init_embed(const float* __restrict__ ea, float* __restrict__ out6) {
  size_t i = (size_t)blockIdx.x * 256 + threadIdx.x;
  out6[i] = DECAYF * ea[i];
}

// ---------------- K2: MFMA distance GEMM + fused argmin -------------------------
#define GBM 128
#define GBN 128
#define GBK 64          // halves per K-step
#define NSTEP (KCAT / GBK)

__device__ __forceinline__ void gload16(const _Float16* g, _Float16* lds) {
  __builtin_amdgcn_global_load_lds((__attribute__((address_space(1))) void*)g,
                                   (__attribute__((address_space(3))) void*)lds, 16, 0, 0);
}

__global__ __launch_bounds__(256) void k_argmin_mfma(const _Float16* __restrict__ Acat,
                                                     const _Float16* __restrict__ Bcat,
                                                     const float* __restrict__ wsq,
                                                     unsigned long long* __restrict__ packed) {
  __shared__ __align__(16) _Float16 As[GBM * GBK];
  __shared__ __align__(16) _Float16 Bs[GBN * GBK];
  __shared__ unsigned long long best[GBM];
  const int tid = threadIdx.x;
  const int w = tid >> 6, l = tid & 63;
  const int lr = l & 15, lc = l >> 4;
  const int wr = w >> 1, wc = w & 1;
  const int n0 = blockIdx.x * GBN, m0 = blockIdx.y * GBM;
  if (tid < GBM) best[tid] = ~0ull;

  floatx4 acc[4][4];
#pragma unroll
  for (int i = 0; i < 4; ++i)
#pragma unroll
    for (int j = 0; j < 4; ++j) acc[i][j] = (floatx4){0.f, 0.f, 0.f, 0.f};

  // staging: LDS linear dest; global source pre-swizzled chunk^(row&7) so the
  // frag ds_read_b128 (row stride 128B) is bank-conflict-free.
  const int srow = (l >> 3);
  const int schk = (l & 7);

  for (int ks = 0; ks < NSTEP; ++ks) {
    const int dbase = ks * GBK;
    __syncthreads();
#pragma unroll
    for (int c = 0; c < 4; ++c) {
      int row = (w * 4 + c) * 8 + srow;
      int sc_ = schk ^ (row & 7);
      gload16(Acat + (size_t)(m0 + row) * KCAT + dbase + sc_ * 8, &As[(w * 4 + c) * 512]);
      gload16(Bcat + (size_t)(n0 + row) * KCAT + dbase + sc_ * 8, &Bs[(w * 4 + c) * 512]);
    }
    __syncthreads();
#pragma unroll
    for (int kk = 0; kk < 2; ++kk) {
      half8 af[4], bf[4];
#pragma unroll
      for (int mi = 0; mi < 4; ++mi) {
        int row = wr * 64 + mi * 16 + lr;
        int ch = (kk * 4 + lc) ^ (row & 7);
        af[mi] = *(const half8*)&As[row * GBK + ch * 8];
      }
#pragma unroll
      for (int ni = 0; ni < 4; ++ni) {
        int row = wc * 64 + ni * 16 + lr;
        int ch = (kk * 4 + lc) ^ (row & 7);
        bf[ni] = *(const half8*)&Bs[row * GBK + ch * 8];
      }
#pragma unroll
      for (int mi = 0; mi < 4; ++mi)
#pragma unroll
        for (int ni = 0; ni < 4; ++ni)
          acc[mi][ni] = __builtin_amdgcn_mfma_f32_16x16x32_f16(af[mi], bf[ni], acc[mi][ni], 0, 0, 0);
    }
  }

  // epilogue: per-row argmin. C layout: col = lane&15, row = (lane>>4)*4 + reg.
  float sc4[4];
  int col4[4];
#pragma unroll
  for (int ni = 0; ni < 4; ++ni) {
    col4[ni] = n0 + wc * 64 + ni * 16 + lr;
    sc4[ni] = wsq[col4[ni]];
  }
#pragma unroll
  for (int mi = 0; mi < 4; ++mi) {
#pragma unroll
    for (int r = 0; r < 4; ++r) {
      unsigned long long bv = ~0ull;
#pragma unroll
      for (int ni = 0; ni < 4; ++ni) {
        float score = fmaf(-2.0f, acc[mi][ni][r], sc4[ni]);
        unsigned u = __float_as_uint(score);
        u ^= (unsigned)(((int)u >> 31) | 0x80000000);  // monotonic float->uint
        unsigned long long p = ((unsigned long long)u << 32) | (unsigned)col4[ni];
        bv = p < bv ? p : bv;
      }
#pragma unroll
      for (int off = 1; off < 16; off <<= 1) {
        unsigned long long o = __shfl_xor(bv, off);
        bv = o < bv ? o : bv;
      }
      if (lr == 0) atomicMin(&best[wr * 64 + mi * 16 + lc * 4 + r], bv);
    }
  }
  __syncthreads();
  if (tid < GBM) atomicMin(&packed[m0 + tid], best[tid]);
}

// ---------------- Fallback fp32 GEMM+argmin -------------------------------------
#define TM 128
#define TN 128
#define DK 32
#define PADL 33
__global__ __launch_bounds__(256) void k_argmin_fp32(const float* __restrict__ zt,
                                                     const float* __restrict__ w,
                                                     const float* __restrict__ wsq,
                                                     unsigned long long* __restrict__ packed) {
  __shared__ float As[TM * PADL];
  __shared__ float Ws[TN * PADL];
  __shared__ unsigned long long best[TM];
  const int tid = threadIdx.x;
  const int k0 = blockIdx.x * TN, m0 = blockIdx.y * TM;
  if (tid < TM) best[tid] = ~0ull;
  const int tx = tid & 15, ty = tid >> 4;
  const int mrow = tid & 127;
  const int q = (tid >> 7) * 16;

  float acc[8][8];
#pragma unroll
  for (int i = 0; i < 8; ++i)
#pragma unroll
    for (int j = 0; j < 8; ++j) acc[i][j] = 0.0f;

  for (int dbase = 0; dbase < DIM; dbase += DK) {
    __syncthreads();
    const float* za = &zt[(size_t)(m0 + mrow) * DIM + dbase + q];
    const float* wa = &w[(size_t)(k0 + mrow) * DIM + dbase + q];
    float4 a0 = *(const float4*)(za + 0), a1 = *(const float4*)(za + 4);
    float4 a2 = *(const float4*)(za + 8), a3 = *(const float4*)(za + 12);
    float4 b0 = *(const float4*)(wa + 0), b1 = *(const float4*)(wa + 4);
    float4 b2 = *(const float4*)(wa + 8), b3 = *(const float4*)(wa + 12);
    float* Ap = &As[mrow * PADL + q];
    float* Wp = &Ws[mrow * PADL + q];
    Ap[0] = a0.x; Ap[1] = a0.y; Ap[2] = a0.z; Ap[3] = a0.w;
    Ap[4] = a1.x; Ap[5] = a1.y; Ap[6] = a1.z; Ap[7] = a1.w;
    Ap[8] = a2.x; Ap[9] = a2.y; Ap[10] = a2.z; Ap[11] = a2.w;
    Ap[12] = a3.x; Ap[13] = a3.y; Ap[14] = a3.z; Ap[15] = a3.w;
    Wp[0] = b0.x; Wp[1] = b0.y; Wp[2] = b0.z; Wp[3] = b0.w;
    Wp[4] = b1.x; Wp[5] = b1.y; Wp[6] = b1.z; Wp[7] = b1.w;
    Wp[8] = b2.x; Wp[9] = b2.y; Wp[10] = b2.z; Wp[11] = b2.w;
    Wp[12] = b3.x; Wp[13] = b3.y; Wp[14] = b3.z; Wp[15] = b3.w;
    __syncthreads();
#pragma unroll
    for (int d = 0; d < DK; ++d) {
      float a[8], b[8];
#pragma unroll
      for (int i = 0; i < 4; ++i) {
        a[i]     = As[(ty * 4 + i) * PADL + d];
        a[4 + i] = As[(64 + ty * 4 + i) * PADL + d];
        b[i]     = Ws[(tx * 4 + i) * PADL + d];
        b[4 + i] = Ws[(64 + tx * 4 + i) * PADL + d];
      }
#pragma unroll
      for (int i = 0; i < 8; ++i)
#pragma unroll
        for (int j = 0; j < 8; ++j) acc[i][j] = fmaf(a[i], b[j], acc[i][j]);
    }
  }

  float sc[8];
  int cols[8];
#pragma unroll
  for (int j = 0; j < 8; ++j) {
    int c = (j < 4) ? tx * 4 + j : 64 + tx * 4 + (j - 4);
    cols[j] = k0 + c;
    sc[j] = wsq[cols[j]];
  }
#pragma unroll
  for (int i = 0; i < 8; ++i) {
    int r = (i < 4) ? ty * 4 + i : 64 + ty * 4 + (i - 4);
    unsigned long long bv = ~0ull;
#pragma unroll
    for (int j = 0; j < 8; ++j) {
      float score = fmaf(-2.0f, acc[i][j], sc[j]);
      unsigned u = __float_as_uint(score);
      u ^= (unsigned)(((int)u >> 31) | 0x80000000);
      unsigned long long p = ((unsigned long long)u << 32) | (unsigned)cols[j];
      bv = p < bv ? p : bv;
    }
    atomicMin(&best[r], bv);
  }
  __syncthreads();
  if (tid < TM) atomicMin(&packed[m0 + tid], best[tid]);
}

// ---------------- K3a: extract indices, histogram counts ------------------------
__global__ void k_idx(const unsigned long long* __restrict__ packed,
                      float* __restrict__ out3, float* __restrict__ counts) {
  int n = blockIdx.x * 256 + threadIdx.x;
  int k = (int)(packed[n] & 0xFFFFFFFFull);
  out3[n] = (float)k;
  atomicAdd(&counts[k], 1.0f);
}

// ---------------- K3b: z_q gather, loss, embed_sum scatter, z_q_st in-place -----
__global__ __launch_bounds__(256) void k_scatter(float* __restrict__ zt,
                                                 const float* __restrict__ w,
                                                 const unsigned long long* __restrict__ packed,
                                                 float* __restrict__ emb_out,
                                                 float* __restrict__ loss_sum) {
  int n = blockIdx.x, d = threadIdx.x;
  int k = (int)(packed[n] & 0xFFFFFFFFull);
  float zv = zt[(size_t)n * DIM + d];
  float wv = w[(size_t)k * DIM + d];
  float diff = wv - zv;                       // z_q - z_perm
  zt[(size_t)n * DIM + d] = zv + diff;        // straight-through
  atomicAdd(&emb_out[(size_t)k * DIM + d], ONEMDECAY * zv);
  float v = diff * diff;
#pragma unroll
  for (int off = 32; off; off >>= 1) v += __shfl_down(v, off);
  __shared__ float red[4];
  if ((threadIdx.x & 63) == 0) red[threadIdx.x >> 6] = v;
  __syncthreads();
  if (threadIdx.x == 0) atomicAdd(loss_sum, red[0] + red[1] + red[2] + red[3]);
}

// ---------------- K4a: new_cluster_size, n_sum, perplexity partial --------------
__global__ void k_cs(const float* __restrict__ cs, const float* __restrict__ counts,
                     float* __restrict__ out5, float* __restrict__ scal) {
  int k = blockIdx.x * 256 + threadIdx.x;
  float c = counts[k];
  float ncs = cs[k] * DECAYF + ONEMDECAY * c;
  out5[k] = ncs;
  float p = c * (1.0f / (float)NZ);
  float t = p * logf(p + 1e-10f);
#pragma unroll
  for (int off = 32; off; off >>= 1) {
    ncs += __shfl_down(ncs, off);
    t += __shfl_down(t, off);
  }
  __shared__ float r1[4], r2[4];
  if ((threadIdx.x & 63) == 0) { r1[threadIdx.x >> 6] = ncs; r2[threadIdx.x >> 6] = t; }
  __syncthreads();
  if (threadIdx.x == 0) {
    atomicAdd(&scal[1], r1[0] + r1[1] + r1[2] + r1[3]);
    atomicAdd(&scal[2], r2[0] + r2[1] + r2[2] + r2[3]);
  }
}

// ---------------- K4b: new_weight + scalars -------------------------------------
__global__ void k_final(const float* __restrict__ emb_out, const float* __restrict__ out5,
                        const float* __restrict__ scal, float* __restrict__ out4,
                        float* __restrict__ out1, float* __restrict__ out2) {
  size_t i = (size_t)blockIdx.x * 256 + threadIdx.x;
  float n = scal[1];
  int k = (int)(i >> 8);
  float ncs = out5[k];
  float smoothed = (ncs + EPSF) / (n + (float)KC * EPSF) * n;
  out4[i] = emb_out[i] / smoothed;
  if (i == 0) {
    out1[0] = BETAF * scal[0] / (float)(NZ * DIM);
    out2[0] = expf(-scal[2]);
  }
}

extern "C" void kernel_launch(void* const* d_in, const int* in_sizes, int n_in,
                              void* d_out, int out_size, void* d_ws, size_t ws_size,
                              hipStream_t stream) {
  const float* z  = (const float*)d_in[0];
  const float* w  = (const float*)d_in[1];
  const float* cs = (const float*)d_in[2];
  const float* ea = (const float*)d_in[3];
  float* out = (float*)d_out;
  float* ws  = (float*)d_ws;

  if (ws_size < (size_t)WS_FLOATS_OLD * sizeof(float)) return;  // fail loudly
  const bool use_mfma = ws_size >= (size_t)WS_FLOATS_NEW * sizeof(float);

  float* zt     = ws + W_ZT;
  float* wsq    = ws + W_WSQ;
  float* counts = ws + W_CNT;
  float* scal   = ws + W_SCAL;
  unsigned long long* packed = (unsigned long long*)(ws + W_PACKED);
  _Float16* Acat = (_Float16*)(ws + W_ACAT);
  _Float16* Bcat = (_Float16*)(ws + W_BCAT);

  float* out0 = out + O_ZQ;
  float* out1 = out + O_LOSS;
  float* out2 = out + O_PERP;
  float* out3 = out + O_IDX;
  float* out4 = out + O_NW;
  float* out5 = out + O_NCS;
  float* out6 = out + O_NEA;

  hipMemsetAsync(counts, 0, (16384 + 4) * sizeof(float), stream);   // counts + scalars
  hipMemsetAsync(packed, 0xFF, (size_t)NZ * sizeof(unsigned long long), stream);

  k_init_embed<<<(KC * DIM) / 256, 256, 0, stream>>>(ea, out6);
  if (use_mfma) {
    k_transpose_in<true><<<dim3(16, 4, NB), 256, 0, stream>>>(z, zt, Acat);
    k_prep_w<true><<<KC / 4, 256, 0, stream>>>(w, wsq, Bcat);
    k_argmin_mfma<<<dim3(KC / GBN, NZ / GBM), 256, 0, stream>>>(Acat, Bcat, wsq, packed);
  } else {
    k_transpose_in<false><<<dim3(16, 4, NB), 256, 0, stream>>>(z, zt, Acat);
    k_prep_w<false><<<KC / 4, 256, 0, stream>>>(w, wsq, Bcat);
    k_argmin_fp32<<<dim3(KC / TN, NZ / TM), 256, 0, stream>>>(zt, w, wsq, packed);
  }
  k_idx<<<NZ / 256, 256, 0, stream>>>(packed, out3, counts);
  k_scatter<<<NZ, 256, 0, stream>>>(zt, w, packed, out6, scal);
  k_cs<<<KC / 256, 256, 0, stream>>>(cs, counts, out5, scal);
  k_final<<<(KC * DIM) / 256, 256, 0, stream>>>(out6, out5, scal, out4, out1, out2);
  k_transpose_out<<<dim3(16, 4, NB), 256, 0, stream>>>(zt, out0);
}

// Round 4
// 468.427 us; speedup vs baseline: 2.4213x; 1.0575x over previous
//
#include <hip/hip_runtime.h>

// Problem constants (from setup_inputs): z (8,256,32,32), weight (16384,256)
#define NB   8
#define DIM  256
#define HW   1024          // 32*32
#define NZ   8192          // NB*HW flattened z rows
#define KC   16384         // codebook entries
#define DECAYF 0.99f
#define ONEMDECAY 0.01f
#define EPSF 1e-5f
#define BETAF 0.25f
#define KCAT 768           // split-GEMM K: [ah|al|ah] . [bh|bh|bl]

typedef _Float16 half8 __attribute__((ext_vector_type(8)));
typedef _Float16 half4 __attribute__((ext_vector_type(4)));
typedef float floatx4 __attribute__((ext_vector_type(4)));

// Output offsets (floats) in d_out, in reference return order
#define O_ZQ   0u
#define O_LOSS 2097152u
#define O_PERP 2097153u
#define O_IDX  2097154u
#define O_NW   2105346u
#define O_NCS  6299650u
#define O_NEA  6316034u

// ws layout (floats)
#define W_ZT     0u          // 8192*256 fp32
#define W_WSQ    2097152u    // 16384
#define W_CNT    2113536u    // 16384
#define W_SCAL   2129920u    // 4: [0]=loss_sum [1]=n_sum [2]=plogp
#define W_PACKED 2129924u    // 8192 u64 (byte off % 8 == 0)
#define W_ACAT   2146308u    // 8192*768 f16 (byte off % 16 == 0)
#define W_BCAT   5292036u    // 16384*768 f16 (byte off % 16 == 0)
#define WS_FLOATS_OLD 2146308u
#define WS_FLOATS_NEW 11583492u

// ---------------- K0: transpose z (b,c,h,w) -> zt[n][d] (+ optional f16 Acat) ---
// Acat segments: [ah | al | ah] so that with Bcat = [bh | bh | bl]:
//   dot = ah.bh + al.bh + ah.bl  (compensated product; only al.bl dropped)
template <bool SPLIT>
__global__ void k_transpose_in(const float* __restrict__ z, float* __restrict__ zt,
                               _Float16* __restrict__ Acat) {
  __shared__ float tile[64][65];
  int hwb = blockIdx.x * 64, db = blockIdx.y * 64, b = blockIdx.z;
  int lane = threadIdx.x & 63, sub = threadIdx.x >> 6;
#pragma unroll
  for (int i = 0; i < 16; ++i) {
    int dof = sub * 16 + i;
    tile[dof][lane] = z[((size_t)(b * DIM + db + dof)) * HW + hwb + lane];
  }
  __syncthreads();
#pragma unroll
  for (int i = 0; i < 16; ++i) {
    int hwof = sub * 16 + i;
    int n = b * HW + hwb + hwof;
    float val = tile[lane][hwof];
    zt[(size_t)n * DIM + db + lane] = val;
    if (SPLIT) {
      _Float16 h = (_Float16)val;
      _Float16 lo = (_Float16)(val - (float)h);
      size_t abase = (size_t)n * KCAT + db + lane;
      Acat[abase] = h;          // seg0 = ah
      Acat[abase + 256] = lo;   // seg1 = al   (pairs with bh)
      Acat[abase + 512] = h;    // seg2 = ah   (pairs with bl)
    }
  }
}

// ---------------- K5: transpose zt[n][d] (holds z_q_st) -> out0 (b,c,h,w) -------
__global__ void k_transpose_out(const float* __restrict__ zt, float* __restrict__ out0) {
  __shared__ float tile[64][65];
  int hwb = blockIdx.x * 64, db = blockIdx.y * 64, b = blockIdx.z;
  int lane = threadIdx.x & 63, sub = threadIdx.x >> 6;
#pragma unroll
  for (int i = 0; i < 16; ++i) {
    int hwof = sub * 16 + i;
    tile[hwof][lane] = zt[((size_t)(b * HW + hwb + hwof)) * DIM + db + lane];
  }
  __syncthreads();
#pragma unroll
  for (int i = 0; i < 16; ++i) {
    int dof = sub * 16 + i;
    out0[((size_t)(b * DIM + db + dof)) * HW + hwb + lane] = tile[lane][dof];
  }
}

// ---------------- K1: wsq[k] = sum_d w[k][d]^2 (fp32) + optional f16 Bcat -------
template <bool SPLIT>
__global__ void k_prep_w(const float* __restrict__ w, float* __restrict__ wsq,
                         _Float16* __restrict__ Bcat) {
  int wave = threadIdx.x >> 6, lane = threadIdx.x & 63;
  int k = blockIdx.x * 4 + wave;
  float4 v = *(const float4*)&w[(size_t)k * DIM + lane * 4];
  float s = v.x * v.x + v.y * v.y + v.z * v.z + v.w * v.w;
#pragma unroll
  for (int off = 32; off; off >>= 1) s += __shfl_down(s, off);
  if (lane == 0) wsq[k] = s;
  if (SPLIT) {
    half4 h = { (_Float16)v.x, (_Float16)v.y, (_Float16)v.z, (_Float16)v.w };
    half4 lo = { (_Float16)(v.x - (float)h.x), (_Float16)(v.y - (float)h.y),
                 (_Float16)(v.z - (float)h.z), (_Float16)(v.w - (float)h.w) };
    size_t bbase = (size_t)k * KCAT + lane * 4;
    *(half4*)&Bcat[bbase] = h;          // seg0 = bh
    *(half4*)&Bcat[bbase + 256] = h;    // seg1 = bh
    *(half4*)&Bcat[bbase + 512] = lo;   // seg2 = bl
  }
}

// ---------------- K1b: init new_embed_avg output with 0.99*embed_avg ------------
__global__ void k_init_embed(const float* __restrict__ ea, float* __restrict__ out6) {
  size_t i = (size_t)blockIdx.x * 256 + threadIdx.x;
  out6[i] = DECAYF * ea[i];
}

// ---------------- K2: MFMA distance GEMM + fused argmin (dbuf + counted vmcnt) --
#define GBM 128
#define GBN 128
#define GBK 64          // halves per K-step
#define NSTEP (KCAT / GBK)

__device__ __forceinline__ void gload16(const _Float16* g, _Float16* lds) {
  __builtin_amdgcn_global_load_lds((__attribute__((address_space(1))) void*)g,
                                   (__attribute__((address_space(3))) void*)lds, 16, 0, 0);
}

#define WAITVM8   asm volatile("s_waitcnt vmcnt(8)" ::: "memory")
#define WAITVM0   asm volatile("s_waitcnt vmcnt(0)" ::: "memory")
#define WAITLGKM0 asm volatile("s_waitcnt lgkmcnt(0)" ::: "memory")
#define BAR       __builtin_amdgcn_s_barrier()

__global__ __launch_bounds__(256) void k_argmin_mfma(const _Float16* __restrict__ Acat,
                                                     const _Float16* __restrict__ Bcat,
                                                     const float* __restrict__ wsq,
                                                     unsigned long long* __restrict__ packed) {
  __shared__ __align__(16) _Float16 As[2][GBM * GBK];
  __shared__ __align__(16) _Float16 Bs[2][GBN * GBK];
  __shared__ unsigned long long best[GBM];
  const int tid = threadIdx.x;
  const int w = tid >> 6, l = tid & 63;
  const int lr = l & 15, lc = l >> 4;
  const int wr = w >> 1, wc = w & 1;
  const int n0 = blockIdx.x * GBN, m0 = blockIdx.y * GBM;
  if (tid < GBM) best[tid] = ~0ull;

  floatx4 acc[4][4];
#pragma unroll
  for (int i = 0; i < 4; ++i)
#pragma unroll
    for (int j = 0; j < 4; ++j) acc[i][j] = (floatx4){0.f, 0.f, 0.f, 0.f};

  // staging: LDS linear dest; global source pre-swizzled chunk^(row&7) so the
  // frag ds_read_b128 (row stride 128B) is bank-conflict-free.
  const int srow = (l >> 3);
  const int schk = (l & 7);

  // 8 gloads per wave per K-step (4 A-row-groups + 4 B-row-groups)
#define STAGE(BUF, STEP)                                                          \
  {                                                                               \
    const int dbase_ = (STEP) * GBK;                                              \
    _Pragma("unroll")                                                             \
    for (int c = 0; c < 4; ++c) {                                                 \
      int row = (w * 4 + c) * 8 + srow;                                           \
      int sc_ = schk ^ (row & 7);                                                 \
      gload16(Acat + (size_t)(m0 + row) * KCAT + dbase_ + sc_ * 8,                \
              &As[BUF][(w * 4 + c) * 512]);                                       \
      gload16(Bcat + (size_t)(n0 + row) * KCAT + dbase_ + sc_ * 8,                \
              &Bs[BUF][(w * 4 + c) * 512]);                                       \
    }                                                                             \
  }

  STAGE(0, 0);
  STAGE(1, 1);

  for (int t = 0; t < NSTEP; ++t) {
    const int b = t & 1;
    if (t < NSTEP - 1) { WAITVM8; } else { WAITVM0; }
    BAR;                                   // all waves' tile-t loads landed
#pragma unroll
    for (int kk = 0; kk < 2; ++kk) {
      half8 af[4], bf[4];
#pragma unroll
      for (int mi = 0; mi < 4; ++mi) {
        int row = wr * 64 + mi * 16 + lr;
        int ch = (kk * 4 + lc) ^ (row & 7);
        af[mi] = *(const half8*)&As[b][row * GBK + ch * 8];
      }
#pragma unroll
      for (int ni = 0; ni < 4; ++ni) {
        int row = wc * 64 + ni * 16 + lr;
        int ch = (kk * 4 + lc) ^ (row & 7);
        bf[ni] = *(const half8*)&Bs[b][row * GBK + ch * 8];
      }
#pragma unroll
      for (int mi = 0; mi < 4; ++mi)
#pragma unroll
        for (int ni = 0; ni < 4; ++ni)
          acc[mi][ni] = __builtin_amdgcn_mfma_f32_16x16x32_f16(af[mi], bf[ni], acc[mi][ni], 0, 0, 0);
    }
    WAITLGKM0;                             // my ds_reads of buf b complete
    BAR;                                   // everyone done reading buf b
    if (t + 2 < NSTEP) STAGE(b, t + 2);    // overwrite freed buffer
  }
#undef STAGE

  // epilogue: per-row argmin. C layout: col = lane&15, row = (lane>>4)*4 + reg.
  float sc4[4];
  int col4[4];
#pragma unroll
  for (int ni = 0; ni < 4; ++ni) {
    col4[ni] = n0 + wc * 64 + ni * 16 + lr;
    sc4[ni] = wsq[col4[ni]];
  }
#pragma unroll
  for (int mi = 0; mi < 4; ++mi) {
#pragma unroll
    for (int r = 0; r < 4; ++r) {
      unsigned long long bv = ~0ull;
#pragma unroll
      for (int ni = 0; ni < 4; ++ni) {
        float score = fmaf(-2.0f, acc[mi][ni][r], sc4[ni]);
        unsigned u = __float_as_uint(score);
        u ^= (unsigned)(((int)u >> 31) | 0x80000000);  // monotonic float->uint
        unsigned long long p = ((unsigned long long)u << 32) | (unsigned)col4[ni];
        bv = p < bv ? p : bv;
      }
#pragma unroll
      for (int off = 1; off < 16; off <<= 1) {
        unsigned long long o = __shfl_xor(bv, off);
        bv = o < bv ? o : bv;
      }
      if (lr == 0) atomicMin(&best[wr * 64 + mi * 16 + lc * 4 + r], bv);
    }
  }
  __syncthreads();
  if (tid < GBM) atomicMin(&packed[m0 + tid], best[tid]);
}

// ---------------- Fallback fp32 GEMM+argmin -------------------------------------
#define TM 128
#define TN 128
#define DK 32
#define PADL 33
__global__ __launch_bounds__(256) void k_argmin_fp32(const float* __restrict__ zt,
                                                     const float* __restrict__ w,
                                                     const float* __restrict__ wsq,
                                                     unsigned long long* __restrict__ packed) {
  __shared__ float As[TM * PADL];
  __shared__ float Ws[TN * PADL];
  __shared__ unsigned long long best[TM];
  const int tid = threadIdx.x;
  const int k0 = blockIdx.x * TN, m0 = blockIdx.y * TM;
  if (tid < TM) best[tid] = ~0ull;
  const int tx = tid & 15, ty = tid >> 4;
  const int mrow = tid & 127;
  const int q = (tid >> 7) * 16;

  float acc[8][8];
#pragma unroll
  for (int i = 0; i < 8; ++i)
#pragma unroll
    for (int j = 0; j < 8; ++j) acc[i][j] = 0.0f;

  for (int dbase = 0; dbase < DIM; dbase += DK) {
    __syncthreads();
    const float* za = &zt[(size_t)(m0 + mrow) * DIM + dbase + q];
    const float* wa = &w[(size_t)(k0 + mrow) * DIM + dbase + q];
    float4 a0 = *(const float4*)(za + 0), a1 = *(const float4*)(za + 4);
    float4 a2 = *(const float4*)(za + 8), a3 = *(const float4*)(za + 12);
    float4 b0 = *(const float4*)(wa + 0), b1 = *(const float4*)(wa + 4);
    float4 b2 = *(const float4*)(wa + 8), b3 = *(const float4*)(wa + 12);
    float* Ap = &As[mrow * PADL + q];
    float* Wp = &Ws[mrow * PADL + q];
    Ap[0] = a0.x; Ap[1] = a0.y; Ap[2] = a0.z; Ap[3] = a0.w;
    Ap[4] = a1.x; Ap[5] = a1.y; Ap[6] = a1.z; Ap[7] = a1.w;
    Ap[8] = a2.x; Ap[9] = a2.y; Ap[10] = a2.z; Ap[11] = a2.w;
    Ap[12] = a3.x; Ap[13] = a3.y; Ap[14] = a3.z; Ap[15] = a3.w;
    Wp[0] = b0.x; Wp[1] = b0.y; Wp[2] = b0.z; Wp[3] = b0.w;
    Wp[4] = b1.x; Wp[5] = b1.y; Wp[6] = b1.z; Wp[7] = b1.w;
    Wp[8] = b2.x; Wp[9] = b2.y; Wp[10] = b2.z; Wp[11] = b2.w;
    Wp[12] = b3.x; Wp[13] = b3.y; Wp[14] = b3.z; Wp[15] = b3.w;
    __syncthreads();
#pragma unroll
    for (int d = 0; d < DK; ++d) {
      float a[8], b[8];
#pragma unroll
      for (int i = 0; i < 4; ++i) {
        a[i]     = As[(ty * 4 + i) * PADL + d];
        a[4 + i] = As[(64 + ty * 4 + i) * PADL + d];
        b[i]     = Ws[(tx * 4 + i) * PADL + d];
        b[4 + i] = Ws[(64 + tx * 4 + i) * PADL + d];
      }
#pragma unroll
      for (int i = 0; i < 8; ++i)
#pragma unroll
        for (int j = 0; j < 8; ++j) acc[i][j] = fmaf(a[i], b[j], acc[i][j]);
    }
  }

  float sc[8];
  int cols[8];
#pragma unroll
  for (int j = 0; j < 8; ++j) {
    int c = (j < 4) ? tx * 4 + j : 64 + tx * 4 + (j - 4);
    cols[j] = k0 + c;
    sc[j] = wsq[cols[j]];
  }
#pragma unroll
  for (int i = 0; i < 8; ++i) {
    int r = (i < 4) ? ty * 4 + i : 64 + ty * 4 + (i - 4);
    unsigned long long bv = ~0ull;
#pragma unroll
    for (int j = 0; j < 8; ++j) {
      float score = fmaf(-2.0f, acc[i][j], sc[j]);
      unsigned u = __float_as_uint(score);
      u ^= (unsigned)(((int)u >> 31) | 0x80000000);
      unsigned long long p = ((unsigned long long)u << 32) | (unsigned)cols[j];
      bv = p < bv ? p : bv;
    }
    atomicMin(&best[r], bv);
  }
  __syncthreads();
  if (tid < TM) atomicMin(&packed[m0 + tid], best[tid]);
}

// ---------------- K3: indices + counts + z_q gather + loss + embed scatter ------
__global__ __launch_bounds__(256) void k_scatter(float* __restrict__ zt,
                                                 const float* __restrict__ w,
                                                 const unsigned long long* __restrict__ packed,
                                                 float* __restrict__ emb_out,
                                                 float* __restrict__ loss_sum,
                                                 float* __restrict__ out3,
                                                 float* __restrict__ counts) {
  int n = blockIdx.x, d = threadIdx.x;
  int k = (int)(packed[n] & 0xFFFFFFFFull);
  if (d == 0) {
    out3[n] = (float)k;
    atomicAdd(&counts[k], 1.0f);
  }
  float zv = zt[(size_t)n * DIM + d];
  float wv = w[(size_t)k * DIM + d];
  float diff = wv - zv;                       // z_q - z_perm
  zt[(size_t)n * DIM + d] = zv + diff;        // straight-through
  atomicAdd(&emb_out[(size_t)k * DIM + d], ONEMDECAY * zv);
  float v = diff * diff;
#pragma unroll
  for (int off = 32; off; off >>= 1) v += __shfl_down(v, off);
  __shared__ float red[4];
  if ((threadIdx.x & 63) == 0) red[threadIdx.x >> 6] = v;
  __syncthreads();
  if (threadIdx.x == 0) atomicAdd(loss_sum, red[0] + red[1] + red[2] + red[3]);
}

// ---------------- K4a: new_cluster_size, n_sum, perplexity partial --------------
__global__ void k_cs(const float* __restrict__ cs, const float* __restrict__ counts,
                     float* __restrict__ out5, float* __restrict__ scal) {
  int k = blockIdx.x * 256 + threadIdx.x;
  float c = counts[k];
  float ncs = cs[k] * DECAYF + ONEMDECAY * c;
  out5[k] = ncs;
  float p = c * (1.0f / (float)NZ);
  float t = p * logf(p + 1e-10f);
#pragma unroll
  for (int off = 32; off; off >>= 1) {
    ncs += __shfl_down(ncs, off);
    t += __shfl_down(t, off);
  }
  __shared__ float r1[4], r2[4];
  if ((threadIdx.x & 63) == 0) { r1[threadIdx.x >> 6] = ncs; r2[threadIdx.x >> 6] = t; }
  __syncthreads();
  if (threadIdx.x == 0) {
    atomicAdd(&scal[1], r1[0] + r1[1] + r1[2] + r1[3]);
    atomicAdd(&scal[2], r2[0] + r2[1] + r2[2] + r2[3]);
  }
}

// ---------------- K4b: new_weight + scalars -------------------------------------
__global__ void k_final(const float* __restrict__ emb_out, const float* __restrict__ out5,
                        const float* __restrict__ scal, float* __restrict__ out4,
                        float* __restrict__ out1, float* __restrict__ out2) {
  size_t i = (size_t)blockIdx.x * 256 + threadIdx.x;
  float n = scal[1];
  int k = (int)(i >> 8);
  float ncs = out5[k];
  float smoothed = (ncs + EPSF) / (n + (float)KC * EPSF) * n;
  out4[i] = emb_out[i] / smoothed;
  if (i == 0) {
    out1[0] = BETAF * scal[0] / (float)(NZ * DIM);
    out2[0] = expf(-scal[2]);
  }
}

extern "C" void kernel_launch(void* const* d_in, const int* in_sizes, int n_in,
                              void* d_out, int out_size, void* d_ws, size_t ws_size,
                              hipStream_t stream) {
  const float* z  = (const float*)d_in[0];
  const float* w  = (const float*)d_in[1];
  const float* cs = (const float*)d_in[2];
  const float* ea = (const float*)d_in[3];
  float* out = (float*)d_out;
  float* ws  = (float*)d_ws;

  if (ws_size < (size_t)WS_FLOATS_OLD * sizeof(float)) return;  // fail loudly
  const bool use_mfma = ws_size >= (size_t)WS_FLOATS_NEW * sizeof(float);

  float* zt     = ws + W_ZT;
  float* wsq    = ws + W_WSQ;
  float* counts = ws + W_CNT;
  float* scal   = ws + W_SCAL;
  unsigned long long* packed = (unsigned long long*)(ws + W_PACKED);
  _Float16* Acat = (_Float16*)(ws + W_ACAT);
  _Float16* Bcat = (_Float16*)(ws + W_BCAT);

  float* out0 = out + O_ZQ;
  float* out1 = out + O_LOSS;
  float* out2 = out + O_PERP;
  float* out3 = out + O_IDX;
  float* out4 = out + O_NW;
  float* out5 = out + O_NCS;
  float* out6 = out + O_NEA;

  hipMemsetAsync(counts, 0, (16384 + 4) * sizeof(float), stream);   // counts + scalars
  hipMemsetAsync(packed, 0xFF, (size_t)NZ * sizeof(unsigned long long), stream);

  k_init_embed<<<(KC * DIM) / 256, 256, 0, stream>>>(ea, out6);
  if (use_mfma) {
    k_transpose_in<true><<<dim3(16, 4, NB), 256, 0, stream>>>(z, zt, Acat);
    k_prep_w<true><<<KC / 4, 256, 0, stream>>>(w, wsq, Bcat);
    k_argmin_mfma<<<dim3(KC / GBN, NZ / GBM), 256, 0, stream>>>(Acat, Bcat, wsq, packed);
  } else {
    k_transpose_in<false><<<dim3(16, 4, NB), 256, 0, stream>>>(z, zt, Acat);
    k_prep_w<false><<<KC / 4, 256, 0, stream>>>(w, wsq, Bcat);
    k_argmin_fp32<<<dim3(KC / TN, NZ / TM), 256, 0, stream>>>(zt, w, wsq, packed);
  }
  k_scatter<<<NZ, 256, 0, stream>>>(zt, w, packed, out6, scal, out3, counts);
  k_cs<<<KC / 256, 256, 0, stream>>>(cs, counts, out5, scal);
  k_final<<<(KC * DIM) / 256, 256, 0, stream>>>(out6, out5, scal, out4, out1, out2);
  k_transpose_out<<<dim3(16, 4, NB), 256, 0, stream>>>(zt, out0);
}